// Round 1
// baseline (843.359 us; speedup 1.0000x reference)
//
#include <hip/hip_runtime.h>

#define HIDDEN 1024
#define EPS 1e-5f

typedef float v2f __attribute__((ext_vector_type(2)));

// Quantize a pair of floats to fp8 e4m3 (OCP, RNE) and back to f32 using the
// gfx950 hardware converters.
__device__ inline void quant_pair(float a, float b, float& qa, float& qb) {
    int packed = __builtin_amdgcn_cvt_pk_fp8_f32(a, b, 0, false);
    v2f d = __builtin_amdgcn_cvt_pk_f32_fp8(packed, false);
    qa = d.x;
    qb = d.y;
}

__global__ __launch_bounds__(256) void bias_ln_fp8_kernel(
    const float* __restrict__ x,
    const float* __restrict__ bias,
    const float* __restrict__ residual,
    const float* __restrict__ gamma,
    const float* __restrict__ beta,
    float* __restrict__ bda_out,
    float* __restrict__ ln_out,
    unsigned int* __restrict__ amax_u,
    int n_rows)
{
    const int lane  = threadIdx.x & 63;
    const int wave  = threadIdx.x >> 6;
    const int gwave = blockIdx.x * 4 + wave;
    const int n_waves = gridDim.x * 4;

    // Per-lane column ownership: chunk j covers float4 index j*64 + lane
    // (consecutive lanes -> consecutive 16B -> perfectly coalesced).
    float4 bv[4], gv[4], btv[4];
    const float4* bias4  = reinterpret_cast<const float4*>(bias);
    const float4* gamma4 = reinterpret_cast<const float4*>(gamma);
    const float4* beta4  = reinterpret_cast<const float4*>(beta);
#pragma unroll
    for (int j = 0; j < 4; ++j) {
        int c4 = j * 64 + lane;
        bv[j]  = bias4[c4];
        gv[j]  = gamma4[c4];
        btv[j] = beta4[c4];
    }

    float local_amax = 0.0f;
    const float inv_d = 1.0f / (float)HIDDEN;

    for (int row = gwave; row < n_rows; row += n_waves) {
        const float4* xr = reinterpret_cast<const float4*>(x + (size_t)row * HIDDEN);
        const float4* rr = reinterpret_cast<const float4*>(residual + (size_t)row * HIDDEN);
        float4* br = reinterpret_cast<float4*>(bda_out + (size_t)row * HIDDEN);
        float4* yr = reinterpret_cast<float4*>(ln_out + (size_t)row * HIDDEN);

        // bda = x + bias + residual; keep whole row in registers, write out.
        float4 v[4];
        float s = 0.0f;
#pragma unroll
        for (int j = 0; j < 4; ++j) {
            int c4 = j * 64 + lane;
            float4 xv = xr[c4];
            float4 rv = rr[c4];
            v[j].x = xv.x + bv[j].x + rv.x;
            v[j].y = xv.y + bv[j].y + rv.y;
            v[j].z = xv.z + bv[j].z + rv.z;
            v[j].w = xv.w + bv[j].w + rv.w;
            br[c4] = v[j];
            s += (v[j].x + v[j].y) + (v[j].z + v[j].w);
        }

        // wave-reduce sum -> mean
#pragma unroll
        for (int off = 32; off >= 1; off >>= 1) s += __shfl_xor(s, off, 64);
        float mu = s * inv_d;

        // variance (two-pass over registers, matches reference formulation)
        float vs = 0.0f;
#pragma unroll
        for (int j = 0; j < 4; ++j) {
            float dx = v[j].x - mu;
            float dy = v[j].y - mu;
            float dz = v[j].z - mu;
            float dw = v[j].w - mu;
            vs += dx * dx + dy * dy + dz * dz + dw * dw;
        }
#pragma unroll
        for (int off = 32; off >= 1; off >>= 1) vs += __shfl_xor(vs, off, 64);
        float rsig = rsqrtf(vs * inv_d + EPS);

        // normalize, affine, amax, fp8 quantize+dequantize, store
#pragma unroll
        for (int j = 0; j < 4; ++j) {
            int c4 = j * 64 + lane;
            float4 yv;
            yv.x = (v[j].x - mu) * rsig * gv[j].x + btv[j].x;
            yv.y = (v[j].y - mu) * rsig * gv[j].y + btv[j].y;
            yv.z = (v[j].z - mu) * rsig * gv[j].z + btv[j].z;
            yv.w = (v[j].w - mu) * rsig * gv[j].w + btv[j].w;
            local_amax = fmaxf(local_amax, fabsf(yv.x));
            local_amax = fmaxf(local_amax, fabsf(yv.y));
            local_amax = fmaxf(local_amax, fabsf(yv.z));
            local_amax = fmaxf(local_amax, fabsf(yv.w));
            float4 qv;
            quant_pair(yv.x, yv.y, qv.x, qv.y);
            quant_pair(yv.z, yv.w, qv.z, qv.w);
            yr[c4] = qv;
        }
    }

    // wave-reduce amax; one device-scope atomic per wave.
#pragma unroll
    for (int off = 32; off >= 1; off >>= 1)
        local_amax = fmaxf(local_amax, __shfl_xor(local_amax, off, 64));
    if (lane == 0)
        atomicMax(amax_u, __float_as_uint(local_amax));  // valid: non-negative floats
}

extern "C" void kernel_launch(void* const* d_in, const int* in_sizes, int n_in,
                              void* d_out, int out_size, void* d_ws, size_t ws_size,
                              hipStream_t stream) {
    const float* x        = (const float*)d_in[0];
    const float* bias     = (const float*)d_in[1];
    const float* residual = (const float*)d_in[2];
    const float* gamma    = (const float*)d_in[3];
    const float* beta     = (const float*)d_in[4];

    const int n_rows = in_sizes[0] / HIDDEN;  // 65536
    float* bda_out = (float*)d_out;
    float* ln_out  = bda_out + (size_t)n_rows * HIDDEN;
    unsigned int* amax_u = (unsigned int*)(ln_out + (size_t)n_rows * HIDDEN);

    // amax slot is poisoned 0xAA before every launch -> zero it on-stream.
    hipMemsetAsync(amax_u, 0, sizeof(unsigned int), stream);

    dim3 grid(2048), block(256);
    hipLaunchKernelGGL(bias_ln_fp8_kernel, grid, block, 0, stream,
                       x, bias, residual, gamma, beta, bda_out, ln_out, amax_u, n_rows);
}